// Round 6
// baseline (362.062 us; speedup 1.0000x reference)
//
#include <hip/hip_runtime.h>
#include <hip/hip_bf16.h>
#include <hip/hip_fp16.h>
#include <hip/hip_cooperative_groups.h>

namespace cg = cooperative_groups;

// Problem constants
#define B_N 32
#define S_N 2048
#define E_N 256
#define H_N 256
#define K2_N 512            // 2E
#define N3_N 768            // 3H
#define M_N (B_N * S_N)     // 65536 rows
#define CCH 64              // scan chunks per sequence
#define LCH (S_N / CCH)     // 32 steps per chunk

typedef __hip_bfloat16 bf16;
typedef __attribute__((ext_vector_type(8))) short bf16x8s;
typedef __attribute__((ext_vector_type(4))) float f32x4;

#define BM 128
#define BN 128
#define BK 32

#define GLOBAL_AS __attribute__((address_space(1)))
#define LDS_AS    __attribute__((address_space(3)))

// R12 post-mortem: (a) fp16-o packing regressed gemm 88->108us (uniform
// slowdown, WRITE ideal) -> REVERTED to R11 fp32 float4 o-store. (b) non-gemm
// time invariant ~153us across 4 different scan implementations -> scans are
// NOT the cost; fixed per-launch overhead + prep dominate. R13: fuse the 3
// scan kernels into ONE cooperative kernel (512 blk x 256 thr, 2 grid.sync;
// phase2 on blocks 0-7). Launches 6->3. Same-wave-same-chunk across phases
// gives L2-warm z/f re-reads in phase 3. Gemm K-loop untouched (T2 swizzle,
// XCD chunking, swapped-operand MFMA epilogue, rcp activations).

__device__ __forceinline__ float sigmoid_fast(float v) {
    return __builtin_amdgcn_rcpf(1.0f + __expf(-v));
}
__device__ __forceinline__ float tanh_fast(float v) {
    return 2.0f * __builtin_amdgcn_rcpf(1.0f + __expf(-2.0f * v)) - 1.0f;
}
__device__ __forceinline__ float bf_lo(uint u) { return __uint_as_float(u << 16); }
__device__ __forceinline__ float bf_hi(uint u) { return __uint_as_float(u & 0xffff0000u); }

// K0: fused x-convert (blocks 0..8191) + W-transpose (blocks 8192..8287).
__global__ __launch_bounds__(256) void prep(
    const float* __restrict__ x, bf16* __restrict__ xb,
    const float* __restrict__ W, bf16* __restrict__ Wt)
{
    const int bid = blockIdx.x;
    if (bid < 8192) {
        if (bid == 0 && threadIdx.x < 32) {
            bf16 z[8] = {};
            *(int4*)(xb - 256 + threadIdx.x * 8) = *(int4*)z;
        }
        size_t i = ((size_t)bid * 256 + threadIdx.x) * 8;
        float4 v0 = *(const float4*)(x + i);
        float4 v1 = *(const float4*)(x + i + 4);
        bf16 t[8];
        t[0] = __float2bfloat16(v0.x); t[1] = __float2bfloat16(v0.y);
        t[2] = __float2bfloat16(v0.z); t[3] = __float2bfloat16(v0.w);
        t[4] = __float2bfloat16(v1.x); t[5] = __float2bfloat16(v1.y);
        t[6] = __float2bfloat16(v1.z); t[7] = __float2bfloat16(v1.w);
        *(int4*)(xb + i) = *(int4*)t;
    } else {
        __shared__ bf16 tile[64][65];
        const int tb = bid - 8192;               // 0..95
        const int k0 = (tb & 7) * 64;            // 8 k-tiles
        const int n0 = (tb >> 3) * 64;           // 12 n-tiles
        const int t  = threadIdx.x;
        const int tr = t >> 6;
        const int tc = t & 63;
        #pragma unroll
        for (int p = 0; p < 16; ++p) {
            int kk = tr + p * 4;
            tile[kk][tc] = __float2bfloat16(W[(size_t)(k0 + kk) * N3_N + n0 + tc]);
        }
        __syncthreads();
        #pragma unroll
        for (int p = 0; p < 16; ++p) {
            int nn = tr + p * 4;
            Wt[(size_t)(n0 + nn) * K2_N + k0 + tc] = tile[tc][nn];
        }
    }
}

// K1: gates GEMM + bias + activation. Swapped-operand MFMA -> direct stores.
__global__ __launch_bounds__(256) void gemm_act(
    const bf16* __restrict__ xb, const bf16* __restrict__ Wt,
    const float* __restrict__ bvec,
    bf16* __restrict__ Zp, __half* __restrict__ Fh, float* __restrict__ Oout)
{
    __shared__ bf16 As[BM][BK];   // unpadded: global_load_lds lane-contiguous dest
    __shared__ bf16 Bs[BN][BK];

    const int tid  = threadIdx.x;
    const int lane = tid & 63;
    const int wave = tid >> 6;
    const int wm   = (wave & 1) * 64;
    const int wn   = (wave >> 1) * 64;
    const int l15  = lane & 15;
    const int quad = lane >> 4;
    const int l4   = lane >> 2;      // chunk row 0..15
    const int q4   = lane & 3;       // k-quarter 0..3
    const int gq   = q4 ^ ((l4 >> 1) & 3);    // swizzled source slot (stage)
    const int swq  = quad ^ ((l15 >> 1) & 3); // swizzled slot (fragment read)

    // XCD-chunked swizzle: 3072 blocks = 8 XCDs x 384, n fastest in-chunk.
    const int wg    = blockIdx.x;
    const int s     = (wg & 7) * 384 + (wg >> 3);
    const int m_idx = s / 6;
    const int n_idx = s - m_idx * 6;
    const int r0    = m_idx * BM;
    const int n0    = n_idx * BN;
    const bool zfix = ((r0 & (S_N - 1)) == 0);  // block row 0 has s==0

    f32x4 acc[4][4] = {};

    for (int kt = 0; kt < K2_N / BK; ++kt) {
        const int k0 = kt * BK;
        const bool second = (k0 >= E_N);   // x_{t-1} half
        __syncthreads();
        #pragma unroll
        for (int cc = 0; cc < 2; ++cc) {
            int c   = wave + cc * 4;
            int row = c * 16 + l4;
            int rA  = r0 + row - (second ? 1 : 0);
            const bf16* ga = xb + (size_t)rA * E_N + (k0 & (E_N - 1)) + gq * 8;
            __builtin_amdgcn_global_load_lds(
                (const GLOBAL_AS void*)ga,
                (LDS_AS void*)&As[c * 16][0], 16, 0, 0);
            const bf16* gb = Wt + (size_t)(n0 + row) * K2_N + k0 + gq * 8;
            __builtin_amdgcn_global_load_lds(
                (const GLOBAL_AS void*)gb,
                (LDS_AS void*)&Bs[c * 16][0], 16, 0, 0);
        }
        __syncthreads();
        if (second && zfix) {
            // global row r0 has s==0: x_prev must be zero. Row 0's slot
            // swizzle f(0)==0 so a linear zero-fill is correct.
            if (tid < 4) {
                bf16 zz[8] = {};
                *(int4*)(&As[0][tid * 8]) = *(int4*)zz;
            }
            __syncthreads();
        }
        bf16x8s a_frag[4], b_frag[4];
        #pragma unroll
        for (int mi = 0; mi < 4; ++mi)
            a_frag[mi] = *(const bf16x8s*)(&As[wm + mi * 16 + l15][swq * 8]);
        #pragma unroll
        for (int ni = 0; ni < 4; ++ni)
            b_frag[ni] = *(const bf16x8s*)(&Bs[wn + ni * 16 + l15][swq * 8]);
        // SWAPPED operands: D^T layout. Lane owns x-row (col dim = l15),
        // W-cols quad*4+j (row dim). Bit-identical element values.
        #pragma unroll
        for (int mi = 0; mi < 4; ++mi)
            #pragma unroll
            for (int ni = 0; ni < 4; ++ni)
                acc[mi][ni] = __builtin_amdgcn_mfma_f32_16x16x32_bf16(
                    b_frag[ni], a_frag[mi], acc[mi][ni], 0, 0, 0);
    }

    // --- epilogue: direct stores, no LDS ---
    // acc[mi][ni][j] = D[row = r0+wm+mi*16+l15][col = n0+wn+ni*16+quad*4+j]
    const int type  = n0 >> 8;          // 0=z(tanh,bf16) 1=f(sig,half) 2=o(sig,f32)
    const int cbase = n0 + wn - type * 256 + quad * 4;
    float4 bias4[4];
    #pragma unroll
    for (int ni = 0; ni < 4; ++ni)
        bias4[ni] = *(const float4*)&bvec[n0 + wn + ni * 16 + quad * 4];

    #pragma unroll
    for (int mi = 0; mi < 4; ++mi) {
        const size_t gr = (size_t)(r0 + wm + mi * 16 + l15) * H_N;
        #pragma unroll
        for (int ni = 0; ni < 4; ++ni) {
            const int col = cbase + ni * 16;
            float v0 = acc[mi][ni][0] + bias4[ni].x;
            float v1 = acc[mi][ni][1] + bias4[ni].y;
            float v2 = acc[mi][ni][2] + bias4[ni].z;
            float v3 = acc[mi][ni][3] + bias4[ni].w;
            if (type == 0) {
                bf16 a0 = __float2bfloat16(tanh_fast(v0));
                bf16 a1 = __float2bfloat16(tanh_fast(v1));
                bf16 a2 = __float2bfloat16(tanh_fast(v2));
                bf16 a3 = __float2bfloat16(tanh_fast(v3));
                uint2 pk;
                pk.x = (uint)*(ushort*)&a0 | ((uint)*(ushort*)&a1 << 16);
                pk.y = (uint)*(ushort*)&a2 | ((uint)*(ushort*)&a3 << 16);
                *(uint2*)(Zp + gr + col) = pk;
            } else if (type == 1) {
                __half a0 = __float2half(sigmoid_fast(v0));
                __half a1 = __float2half(sigmoid_fast(v1));
                __half a2 = __float2half(sigmoid_fast(v2));
                __half a3 = __float2half(sigmoid_fast(v3));
                uint2 pk;
                pk.x = (uint)*(ushort*)&a0 | ((uint)*(ushort*)&a1 << 16);
                pk.y = (uint)*(ushort*)&a2 | ((uint)*(ushort*)&a3 << 16);
                *(uint2*)(Fh + gr + col) = pk;
            } else {
                float4 vv = make_float4(sigmoid_fast(v0), sigmoid_fast(v1),
                                        sigmoid_fast(v2), sigmoid_fast(v3));
                *(float4*)(Oout + gr + col) = vv;
            }
        }
    }
}

// K2: fused 3-phase scan, cooperative launch (512 blocks x 256 threads).
// Phase 1: wave-per-chunk local scan -> Cend/Pprod.
// Phase 2: blocks 0-7 (2048 threads) do the 64-step chunk prefix -> Cstart.
// Phase 3: wave-per-chunk replay; o read fp32 from outH rows, h written over.
__global__ __launch_bounds__(256) void scan_fused(
    const bf16* __restrict__ Zp, const __half* __restrict__ Fh,
    const int* __restrict__ mask,
    float* __restrict__ Cend, float* __restrict__ Pprod,
    float* __restrict__ Cstart,
    float* __restrict__ outH, float* __restrict__ outHid,
    float* __restrict__ outCell)
{
    cg::grid_group grid = cg::this_grid();
    const int wave = threadIdx.x >> 6;
    const int lane = threadIdx.x & 63;
    const int bc   = blockIdx.x * 4 + wave;      // chunk id 0..2047
    const int hc   = lane * 4;

    // --- Phase 1: local scan ---
    {
        size_t base = (size_t)bc * LCH * H_N + hc;
        float c0 = 0.f, c1 = 0.f, c2 = 0.f, c3 = 0.f;
        float P0 = 1.f, P1 = 1.f, P2 = 1.f, P3 = 1.f;
        #pragma unroll 4
        for (int t = 0; t < LCH; ++t) {
            uint2 zz = *(const uint2*)(Zp + base);
            uint2 ff = *(const uint2*)(Fh + base);
            float z0 = bf_lo(zz.x), z1 = bf_hi(zz.x), z2 = bf_lo(zz.y), z3 = bf_hi(zz.y);
            float2 fa = __half22float2(*(const __half2*)&ff.x);
            float2 fb = __half22float2(*(const __half2*)&ff.y);
            c0 = fa.x * c0 + (1.f - fa.x) * z0;  P0 *= fa.x;
            c1 = fa.y * c1 + (1.f - fa.y) * z1;  P1 *= fa.y;
            c2 = fb.x * c2 + (1.f - fb.x) * z2;  P2 *= fb.x;
            c3 = fb.y * c3 + (1.f - fb.y) * z3;  P3 *= fb.y;
            base += H_N;
        }
        *(float4*)(Cend  + (size_t)bc * H_N + hc) = make_float4(c0, c1, c2, c3);
        *(float4*)(Pprod + (size_t)bc * H_N + hc) = make_float4(P0, P1, P2, P3);
    }

    grid.sync();

    // --- Phase 2: chunk prefix (blocks 0-7 = 2048 threads) ---
    if (blockIdx.x < 8) {
        const int gid = blockIdx.x * 256 + threadIdx.x;  // 0..2047
        const int b   = gid >> 6;
        const int hp  = (gid & 63) * 4;
        float4 cs = make_float4(0.f, 0.f, 0.f, 0.f);
        #pragma unroll 8
        for (int ch = 0; ch < CCH; ++ch) {
            size_t idx = (size_t)(b * CCH + ch) * H_N + hp;
            *(float4*)(Cstart + idx) = cs;
            float4 ce = *(const float4*)(Cend + idx);
            float4 pp = *(const float4*)(Pprod + idx);
            cs.x = ce.x + pp.x * cs.x;
            cs.y = ce.y + pp.y * cs.y;
            cs.z = ce.z + pp.z * cs.z;
            cs.w = ce.w + pp.w * cs.w;
        }
    }

    grid.sync();

    // --- Phase 3: replay (z/f L2-warm from phase 1, same wave same chunk) ---
    {
        const int b  = bc >> 6;                  // bc / CCH
        float4 cs = *(const float4*)(Cstart + (size_t)bc * H_N + hc);
        float c0 = cs.x, c1 = cs.y, c2 = cs.z, c3 = cs.w;
        int tgt = mask[b] - 1;
        tgt = (tgt < 0) ? 0 : ((tgt > S_N - 1) ? (S_N - 1) : tgt);
        const int s0 = (bc & (CCH - 1)) * LCH;
        const size_t rowbase = (size_t)bc * LCH;

        for (int t = 0; t < LCH; ++t) {
            size_t r = rowbase + t;
            uint2 zz = *(const uint2*)(Zp + r * H_N + hc);
            uint2 ff = *(const uint2*)(Fh + r * H_N + hc);
            float4 oo = *(const float4*)(outH + r * H_N + hc);
            float z0 = bf_lo(zz.x), z1 = bf_hi(zz.x), z2 = bf_lo(zz.y), z3 = bf_hi(zz.y);
            float2 fa = __half22float2(*(const __half2*)&ff.x);
            float2 fb = __half22float2(*(const __half2*)&ff.y);
            c0 = fa.x * c0 + (1.f - fa.x) * z0;
            c1 = fa.y * c1 + (1.f - fa.y) * z1;
            c2 = fb.x * c2 + (1.f - fb.x) * z2;
            c3 = fb.y * c3 + (1.f - fb.y) * z3;
            float4 hv = make_float4(oo.x * c0, oo.y * c1, oo.z * c2, oo.w * c3);
            *(float4*)(outH + r * H_N + hc) = hv;
            if (s0 + t == tgt) {
                *(float4*)(outHid  + (size_t)b * H_N + hc) = hv;
                *(float4*)(outCell + (size_t)b * H_N + hc) = make_float4(c0, c1, c2, c3);
            }
        }
    }
}

extern "C" void kernel_launch(void* const* d_in, const int* in_sizes, int n_in,
                              void* d_out, int out_size, void* d_ws, size_t ws_size,
                              hipStream_t stream) {
    const float* x = nullptr; const int* mask = nullptr;
    const float* W = nullptr; const float* bvec = nullptr;
    for (int i = 0; i < n_in; ++i) {
        switch (in_sizes[i]) {
            case M_N * E_N:     x    = (const float*)d_in[i]; break;
            case B_N:           mask = (const int*)d_in[i]; break;
            case K2_N * N3_N:   W    = (const float*)d_in[i]; break;
            case N3_N:          bvec = (const float*)d_in[i]; break;
        }
    }

    float* out     = (float*)d_out;
    float* outHid  = out + (size_t)M_N * H_N;
    float* outCell = outHid + (size_t)B_N * H_N;

    bf16*   xb = (bf16*)d_ws + 256;
    bf16*   Wt = xb + (size_t)M_N * E_N;
    bf16*   Zp = Wt + (size_t)N3_N * K2_N;
    __half* Fh = (__half*)(Zp + (size_t)M_N * H_N);
    float* Cend   = (float*)(Fh + (size_t)M_N * H_N);
    float* Pprod  = Cend + (size_t)B_N * CCH * H_N;
    float* Cstart = Pprod + (size_t)B_N * CCH * H_N;

    prep<<<8192 + 96, 256, 0, stream>>>(x, xb, W, Wt);

    gemm_act<<<(M_N / BM) * (N3_N / BN), 256, 0, stream>>>(xb, Wt, bvec, Zp, Fh, out);

    const bf16* Zc = Zp; const __half* Fc = Fh;
    void* args[] = {
        (void*)&Zc, (void*)&Fc, (void*)&mask,
        (void*)&Cend, (void*)&Pprod, (void*)&Cstart,
        (void*)&out, (void*)&outHid, (void*)&outCell
    };
    hipLaunchCooperativeKernel((void*)scan_fused, dim3(B_N * CCH / 4), dim3(256),
                               args, 0, stream);
}

// Round 7
// 244.717 us; speedup vs baseline: 1.4795x; 1.4795x over previous
//
#include <hip/hip_runtime.h>
#include <hip/hip_bf16.h>
#include <hip/hip_fp16.h>

// Problem constants
#define B_N 32
#define S_N 2048
#define E_N 256
#define H_N 256
#define K2_N 512            // 2E
#define N3_N 768            // 3H
#define M_N (B_N * S_N)     // 65536 rows
#define CCH 64              // scan chunks per sequence
#define LCH (S_N / CCH)     // 32 steps per chunk

typedef __hip_bfloat16 bf16;
typedef __attribute__((ext_vector_type(8))) short bf16x8s;
typedef __attribute__((ext_vector_type(4))) float f32x4;

#define BM 128
#define BN 128
#define BK 32

#define GLOBAL_AS __attribute__((address_space(1)))
#define LDS_AS    __attribute__((address_space(3)))

// R13 post-mortem: coop fusion regressed (362us) but MEASURED the scans:
// 155us @ VALUBusy 2.6% -> pure latency-bound. R8/R11/R13 scan variants all
// ~140-155us because in-flight bytes/CU (~4-8KB) << ~22KB needed to cover
// ~900cy HBM latency at 6TB/s (in-flight = waves x loads-ahead x bytes;
// the variants traded waves vs bytes/load, product constant). R14: revert
// to split launches (gemm = R11's 88us version exactly); scans get BOTH
// max TLP (2048 blocks, block-per-chunk, 32 waves/CU) AND 8-deep explicit
// load batching into static-indexed reg arrays (compile-time idx, no
// scratch) -> 8-24 outstanding loads/thread. Predicted scans 140 -> ~55us.

__device__ __forceinline__ float sigmoid_fast(float v) {
    return __builtin_amdgcn_rcpf(1.0f + __expf(-v));
}
__device__ __forceinline__ float tanh_fast(float v) {
    return 2.0f * __builtin_amdgcn_rcpf(1.0f + __expf(-2.0f * v)) - 1.0f;
}
__device__ __forceinline__ float bf2f(ushort u) {
    return __uint_as_float((uint)u << 16);
}

// K0: fused x-convert (blocks 0..8191) + W-transpose (blocks 8192..8287).
__global__ __launch_bounds__(256) void prep(
    const float* __restrict__ x, bf16* __restrict__ xb,
    const float* __restrict__ W, bf16* __restrict__ Wt)
{
    const int bid = blockIdx.x;
    if (bid < 8192) {
        if (bid == 0 && threadIdx.x < 32) {
            bf16 z[8] = {};
            *(int4*)(xb - 256 + threadIdx.x * 8) = *(int4*)z;
        }
        size_t i = ((size_t)bid * 256 + threadIdx.x) * 8;
        float4 v0 = *(const float4*)(x + i);
        float4 v1 = *(const float4*)(x + i + 4);
        bf16 t[8];
        t[0] = __float2bfloat16(v0.x); t[1] = __float2bfloat16(v0.y);
        t[2] = __float2bfloat16(v0.z); t[3] = __float2bfloat16(v0.w);
        t[4] = __float2bfloat16(v1.x); t[5] = __float2bfloat16(v1.y);
        t[6] = __float2bfloat16(v1.z); t[7] = __float2bfloat16(v1.w);
        *(int4*)(xb + i) = *(int4*)t;
    } else {
        __shared__ bf16 tile[64][65];
        const int tb = bid - 8192;               // 0..95
        const int k0 = (tb & 7) * 64;            // 8 k-tiles
        const int n0 = (tb >> 3) * 64;           // 12 n-tiles
        const int t  = threadIdx.x;
        const int tr = t >> 6;
        const int tc = t & 63;
        #pragma unroll
        for (int p = 0; p < 16; ++p) {
            int kk = tr + p * 4;
            tile[kk][tc] = __float2bfloat16(W[(size_t)(k0 + kk) * N3_N + n0 + tc]);
        }
        __syncthreads();
        #pragma unroll
        for (int p = 0; p < 16; ++p) {
            int nn = tr + p * 4;
            Wt[(size_t)(n0 + nn) * K2_N + k0 + tc] = tile[tc][nn];
        }
    }
}

// K1: gates GEMM + bias + activation. Swapped-operand MFMA -> direct stores.
__global__ __launch_bounds__(256) void gemm_act(
    const bf16* __restrict__ xb, const bf16* __restrict__ Wt,
    const float* __restrict__ bvec,
    bf16* __restrict__ Zp, __half* __restrict__ Fh, float* __restrict__ Oout)
{
    __shared__ bf16 As[BM][BK];   // unpadded: global_load_lds lane-contiguous dest
    __shared__ bf16 Bs[BN][BK];

    const int tid  = threadIdx.x;
    const int lane = tid & 63;
    const int wave = tid >> 6;
    const int wm   = (wave & 1) * 64;
    const int wn   = (wave >> 1) * 64;
    const int l15  = lane & 15;
    const int quad = lane >> 4;
    const int l4   = lane >> 2;      // chunk row 0..15
    const int q4   = lane & 3;       // k-quarter 0..3
    const int gq   = q4 ^ ((l4 >> 1) & 3);    // swizzled source slot (stage)
    const int swq  = quad ^ ((l15 >> 1) & 3); // swizzled slot (fragment read)

    // XCD-chunked swizzle: 3072 blocks = 8 XCDs x 384, n fastest in-chunk.
    const int wg    = blockIdx.x;
    const int s     = (wg & 7) * 384 + (wg >> 3);
    const int m_idx = s / 6;
    const int n_idx = s - m_idx * 6;
    const int r0    = m_idx * BM;
    const int n0    = n_idx * BN;
    const bool zfix = ((r0 & (S_N - 1)) == 0);  // block row 0 has s==0

    f32x4 acc[4][4] = {};

    for (int kt = 0; kt < K2_N / BK; ++kt) {
        const int k0 = kt * BK;
        const bool second = (k0 >= E_N);   // x_{t-1} half
        __syncthreads();
        #pragma unroll
        for (int cc = 0; cc < 2; ++cc) {
            int c   = wave + cc * 4;
            int row = c * 16 + l4;
            int rA  = r0 + row - (second ? 1 : 0);
            const bf16* ga = xb + (size_t)rA * E_N + (k0 & (E_N - 1)) + gq * 8;
            __builtin_amdgcn_global_load_lds(
                (const GLOBAL_AS void*)ga,
                (LDS_AS void*)&As[c * 16][0], 16, 0, 0);
            const bf16* gb = Wt + (size_t)(n0 + row) * K2_N + k0 + gq * 8;
            __builtin_amdgcn_global_load_lds(
                (const GLOBAL_AS void*)gb,
                (LDS_AS void*)&Bs[c * 16][0], 16, 0, 0);
        }
        __syncthreads();
        if (second && zfix) {
            // global row r0 has s==0: x_prev must be zero. Row 0's slot
            // swizzle f(0)==0 so a linear zero-fill is correct.
            if (tid < 4) {
                bf16 zz[8] = {};
                *(int4*)(&As[0][tid * 8]) = *(int4*)zz;
            }
            __syncthreads();
        }
        bf16x8s a_frag[4], b_frag[4];
        #pragma unroll
        for (int mi = 0; mi < 4; ++mi)
            a_frag[mi] = *(const bf16x8s*)(&As[wm + mi * 16 + l15][swq * 8]);
        #pragma unroll
        for (int ni = 0; ni < 4; ++ni)
            b_frag[ni] = *(const bf16x8s*)(&Bs[wn + ni * 16 + l15][swq * 8]);
        // SWAPPED operands: D^T layout. Lane owns x-row (col dim = l15),
        // W-cols quad*4+j (row dim). Bit-identical element values.
        #pragma unroll
        for (int mi = 0; mi < 4; ++mi)
            #pragma unroll
            for (int ni = 0; ni < 4; ++ni)
                acc[mi][ni] = __builtin_amdgcn_mfma_f32_16x16x32_bf16(
                    b_frag[ni], a_frag[mi], acc[mi][ni], 0, 0, 0);
    }

    // --- epilogue: direct stores, no LDS ---
    // acc[mi][ni][j] = D[row = r0+wm+mi*16+l15][col = n0+wn+ni*16+quad*4+j]
    const int type  = n0 >> 8;          // 0=z(tanh,bf16) 1=f(sig,half) 2=o(sig,f32)
    const int cbase = n0 + wn - type * 256 + quad * 4;
    float4 bias4[4];
    #pragma unroll
    for (int ni = 0; ni < 4; ++ni)
        bias4[ni] = *(const float4*)&bvec[n0 + wn + ni * 16 + quad * 4];

    #pragma unroll
    for (int mi = 0; mi < 4; ++mi) {
        const size_t gr = (size_t)(r0 + wm + mi * 16 + l15) * H_N;
        #pragma unroll
        for (int ni = 0; ni < 4; ++ni) {
            const int col = cbase + ni * 16;
            float v0 = acc[mi][ni][0] + bias4[ni].x;
            float v1 = acc[mi][ni][1] + bias4[ni].y;
            float v2 = acc[mi][ni][2] + bias4[ni].z;
            float v3 = acc[mi][ni][3] + bias4[ni].w;
            if (type == 0) {
                bf16 a0 = __float2bfloat16(tanh_fast(v0));
                bf16 a1 = __float2bfloat16(tanh_fast(v1));
                bf16 a2 = __float2bfloat16(tanh_fast(v2));
                bf16 a3 = __float2bfloat16(tanh_fast(v3));
                uint2 pk;
                pk.x = (uint)*(ushort*)&a0 | ((uint)*(ushort*)&a1 << 16);
                pk.y = (uint)*(ushort*)&a2 | ((uint)*(ushort*)&a3 << 16);
                *(uint2*)(Zp + gr + col) = pk;
            } else if (type == 1) {
                __half a0 = __float2half(sigmoid_fast(v0));
                __half a1 = __float2half(sigmoid_fast(v1));
                __half a2 = __float2half(sigmoid_fast(v2));
                __half a3 = __float2half(sigmoid_fast(v3));
                uint2 pk;
                pk.x = (uint)*(ushort*)&a0 | ((uint)*(ushort*)&a1 << 16);
                pk.y = (uint)*(ushort*)&a2 | ((uint)*(ushort*)&a3 << 16);
                *(uint2*)(Fh + gr + col) = pk;
            } else {
                float4 vv = make_float4(sigmoid_fast(v0), sigmoid_fast(v1),
                                        sigmoid_fast(v2), sigmoid_fast(v3));
                *(float4*)(Oout + gr + col) = vv;
            }
        }
    }
}

// K2: per-chunk local scan. Block-per-chunk (2048 blocks), 1 col/thread,
// 8-deep explicit load batching (static reg indices -> no scratch).
__global__ __launch_bounds__(256) void scan_part1(
    const ushort* __restrict__ Zp, const ushort* __restrict__ Fh,
    float* __restrict__ Cend, float* __restrict__ Pprod)
{
    const int bc = blockIdx.x;          // chunk 0..2047
    const int h  = threadIdx.x;         // col
    size_t base = (size_t)bc * LCH * H_N + h;
    float c = 0.f, P = 1.f;
    #pragma unroll
    for (int tt = 0; tt < LCH; tt += 8) {
        ushort zr[8], fr[8];
        #pragma unroll
        for (int k = 0; k < 8; ++k) {
            zr[k] = Zp[base + (size_t)k * H_N];
            fr[k] = Fh[base + (size_t)k * H_N];
        }
        #pragma unroll
        for (int k = 0; k < 8; ++k) {
            float z = bf2f(zr[k]);
            float f = __half2float(*(const __half*)&fr[k]);
            c = f * c + (1.f - f) * z;
            P *= f;
        }
        base += (size_t)8 * H_N;
    }
    Cend[(size_t)bc * H_N + h]  = c;
    Pprod[(size_t)bc * H_N + h] = P;
}

// K3: sequential scan across chunks. 4 h-cols/thread, float4, unrolled.
__global__ __launch_bounds__(256) void scan_part2(
    const float* __restrict__ Cend, const float* __restrict__ Pprod,
    float* __restrict__ Cstart)
{
    const int gid = blockIdx.x * 256 + threadIdx.x;  // 0..2047
    const int b   = gid >> 6;
    const int hc  = (gid & 63) * 4;
    float4 cs = make_float4(0.f, 0.f, 0.f, 0.f);
    #pragma unroll 8
    for (int ch = 0; ch < CCH; ++ch) {
        size_t idx = (size_t)(b * CCH + ch) * H_N + hc;
        *(float4*)(Cstart + idx) = cs;
        float4 ce = *(const float4*)(Cend + idx);
        float4 pp = *(const float4*)(Pprod + idx);
        cs.x = ce.x + pp.x * cs.x;
        cs.y = ce.y + pp.y * cs.y;
        cs.z = ce.z + pp.z * cs.z;
        cs.w = ce.w + pp.w * cs.w;
    }
}

// K4: replay chunk. Block-per-chunk (2048 blocks), 1 col/thread, 8-deep
// load batching; o read fp32 from outH rows, h written over (same thread,
// program-ordered, addresses touched exactly once).
__global__ __launch_bounds__(256) void scan_part3(
    const ushort* __restrict__ Zp, const ushort* __restrict__ Fh,
    const float* __restrict__ Cstart, const int* __restrict__ mask,
    float* __restrict__ outH, float* __restrict__ outHid, float* __restrict__ outCell)
{
    const int bc = blockIdx.x;          // chunk 0..2047
    const int b  = bc >> 6;             // bc / CCH
    const int h  = threadIdx.x;
    float c = Cstart[(size_t)bc * H_N + h];
    int tgt = mask[b] - 1;
    tgt = (tgt < 0) ? 0 : ((tgt > S_N - 1) ? (S_N - 1) : tgt);
    const int s0 = (bc & (CCH - 1)) * LCH;
    size_t base = (size_t)bc * LCH * H_N + h;

    #pragma unroll
    for (int tt = 0; tt < LCH; tt += 8) {
        ushort zr[8], fr[8];
        float orr[8];
        #pragma unroll
        for (int k = 0; k < 8; ++k) {
            zr[k]  = Zp[base + (size_t)k * H_N];
            fr[k]  = Fh[base + (size_t)k * H_N];
            orr[k] = outH[base + (size_t)k * H_N];
        }
        #pragma unroll
        for (int k = 0; k < 8; ++k) {
            float z = bf2f(zr[k]);
            float f = __half2float(*(const __half*)&fr[k]);
            c = f * c + (1.f - f) * z;
            float hv = orr[k] * c;
            outH[base + (size_t)k * H_N] = hv;
            if (s0 + tt + k == tgt) {
                outHid[(size_t)b * H_N + h]  = hv;
                outCell[(size_t)b * H_N + h] = c;
            }
        }
        base += (size_t)8 * H_N;
    }
}

extern "C" void kernel_launch(void* const* d_in, const int* in_sizes, int n_in,
                              void* d_out, int out_size, void* d_ws, size_t ws_size,
                              hipStream_t stream) {
    const float* x = nullptr; const int* mask = nullptr;
    const float* W = nullptr; const float* bvec = nullptr;
    for (int i = 0; i < n_in; ++i) {
        switch (in_sizes[i]) {
            case M_N * E_N:     x    = (const float*)d_in[i]; break;
            case B_N:           mask = (const int*)d_in[i]; break;
            case K2_N * N3_N:   W    = (const float*)d_in[i]; break;
            case N3_N:          bvec = (const float*)d_in[i]; break;
        }
    }

    float* out     = (float*)d_out;
    float* outHid  = out + (size_t)M_N * H_N;
    float* outCell = outHid + (size_t)B_N * H_N;

    bf16*   xb = (bf16*)d_ws + 256;
    bf16*   Wt = xb + (size_t)M_N * E_N;
    bf16*   Zp = Wt + (size_t)N3_N * K2_N;
    __half* Fh = (__half*)(Zp + (size_t)M_N * H_N);
    float* Cend   = (float*)(Fh + (size_t)M_N * H_N);
    float* Pprod  = Cend + (size_t)B_N * CCH * H_N;
    float* Cstart = Pprod + (size_t)B_N * CCH * H_N;

    prep<<<8192 + 96, 256, 0, stream>>>(x, xb, W, Wt);

    gemm_act<<<(M_N / BM) * (N3_N / BN), 256, 0, stream>>>(xb, Wt, bvec, Zp, Fh, out);
    scan_part1<<<B_N * CCH, 256, 0, stream>>>((const ushort*)Zp, (const ushort*)Fh,
                                              Cend, Pprod);
    scan_part2<<<B_N * (H_N / 4) / 256, 256, 0, stream>>>(Cend, Pprod, Cstart);
    scan_part3<<<B_N * CCH, 256, 0, stream>>>((const ushort*)Zp, (const ushort*)Fh,
                                              Cstart, mask, out, outHid, outCell);
}

// Round 8
// 241.238 us; speedup vs baseline: 1.5009x; 1.0144x over previous
//
#include <hip/hip_runtime.h>
#include <hip/hip_bf16.h>
#include <hip/hip_fp16.h>

// Problem constants
#define B_N 32
#define S_N 2048
#define E_N 256
#define H_N 256
#define K2_N 512            // 2E
#define N3_N 768            // 3H
#define M_N (B_N * S_N)     // 65536 rows
#define CCH 64              // scan chunks per sequence
#define LCH (S_N / CCH)     // 32 steps per chunk

typedef __hip_bfloat16 bf16;
typedef __attribute__((ext_vector_type(8))) short bf16x8s;
typedef __attribute__((ext_vector_type(4))) float f32x4;

#define BM 128
#define BN 128
#define BK 32

#define GLOBAL_AS __attribute__((address_space(1)))
#define LDS_AS    __attribute__((address_space(3)))

// R14 post-mortem: scan batching = no change (244.7 ~= R11 241); R13's
// "scans=155us" was confounded (coop kernel had 8 waves/CU + gridsync) -
// retract. Known-hot: gemm 88us vs 26us traffic / 20us MFMA rooflines.
// Mechanism = m97 barrier drain: __syncthreads emits vmcnt(0), draining the
// global_load_lds queue 16x per block. R15: 2-phase LDS double-buffer with
// counted vmcnt (T3/T4 minimum recipe): stage(next); vmcnt(4); sched_barrier;
// raw s_barrier; ds_read+MFMA(cur); raw s_barrier. No vmcnt(0) in the loop.
// zfix rebuilt as address-select: second-half row-0 loads read the pre-zeroed
// guard row (rA=-1) -> no LDS patch, no extra barrier. Reuse distance of a
// buffer = 2 barriers (stage at iter k targets buf computed at iter k-1,
// issued after iter k-1's trailing barrier => all waves done reading). Scans/
// prep untouched (R14 versions).

__device__ __forceinline__ float sigmoid_fast(float v) {
    return __builtin_amdgcn_rcpf(1.0f + __expf(-v));
}
__device__ __forceinline__ float tanh_fast(float v) {
    return 2.0f * __builtin_amdgcn_rcpf(1.0f + __expf(-2.0f * v)) - 1.0f;
}
__device__ __forceinline__ float bf2f(ushort u) {
    return __uint_as_float((uint)u << 16);
}

// K0: fused x-convert (blocks 0..8191) + W-transpose (blocks 8192..8287).
__global__ __launch_bounds__(256) void prep(
    const float* __restrict__ x, bf16* __restrict__ xb,
    const float* __restrict__ W, bf16* __restrict__ Wt)
{
    const int bid = blockIdx.x;
    if (bid < 8192) {
        if (bid == 0 && threadIdx.x < 32) {
            bf16 z[8] = {};
            *(int4*)(xb - 256 + threadIdx.x * 8) = *(int4*)z;
        }
        size_t i = ((size_t)bid * 256 + threadIdx.x) * 8;
        float4 v0 = *(const float4*)(x + i);
        float4 v1 = *(const float4*)(x + i + 4);
        bf16 t[8];
        t[0] = __float2bfloat16(v0.x); t[1] = __float2bfloat16(v0.y);
        t[2] = __float2bfloat16(v0.z); t[3] = __float2bfloat16(v0.w);
        t[4] = __float2bfloat16(v1.x); t[5] = __float2bfloat16(v1.y);
        t[6] = __float2bfloat16(v1.z); t[7] = __float2bfloat16(v1.w);
        *(int4*)(xb + i) = *(int4*)t;
    } else {
        __shared__ bf16 tile[64][65];
        const int tb = bid - 8192;               // 0..95
        const int k0 = (tb & 7) * 64;            // 8 k-tiles
        const int n0 = (tb >> 3) * 64;           // 12 n-tiles
        const int t  = threadIdx.x;
        const int tr = t >> 6;
        const int tc = t & 63;
        #pragma unroll
        for (int p = 0; p < 16; ++p) {
            int kk = tr + p * 4;
            tile[kk][tc] = __float2bfloat16(W[(size_t)(k0 + kk) * N3_N + n0 + tc]);
        }
        __syncthreads();
        #pragma unroll
        for (int p = 0; p < 16; ++p) {
            int nn = tr + p * 4;
            Wt[(size_t)(n0 + nn) * K2_N + k0 + tc] = tile[tc][nn];
        }
    }
}

// K1: gates GEMM + bias + activation. Double-buffered staging, counted vmcnt.
__global__ __launch_bounds__(256) void gemm_act(
    const bf16* __restrict__ xb, const bf16* __restrict__ Wt,
    const float* __restrict__ bvec,
    bf16* __restrict__ Zp, __half* __restrict__ Fh, float* __restrict__ Oout)
{
    __shared__ bf16 As[2][BM][BK];   // 2 x 8 KiB
    __shared__ bf16 Bs[2][BN][BK];   // 2 x 8 KiB

    const int tid  = threadIdx.x;
    const int lane = tid & 63;
    const int wave = tid >> 6;
    const int wm   = (wave & 1) * 64;
    const int wn   = (wave >> 1) * 64;
    const int l15  = lane & 15;
    const int quad = lane >> 4;
    const int l4   = lane >> 2;      // chunk row 0..15
    const int q4   = lane & 3;       // k-quarter 0..3
    const int gq   = q4 ^ ((l4 >> 1) & 3);    // swizzled source slot (stage)
    const int swq  = quad ^ ((l15 >> 1) & 3); // swizzled slot (fragment read)

    // XCD-chunked swizzle: 3072 blocks = 8 XCDs x 384, n fastest in-chunk.
    const int wg    = blockIdx.x;
    const int s     = (wg & 7) * 384 + (wg >> 3);
    const int m_idx = s / 6;
    const int n_idx = s - m_idx * 6;
    const int r0    = m_idx * BM;
    const int n0    = n_idx * BN;
    const bool zfix = ((r0 & (S_N - 1)) == 0);  // block row 0 has s==0

    f32x4 acc[4][4] = {};

    // Stage tile kt into buffer pb. Row-0 second-half reads the guard row
    // (zeros) when this block's first global row has s==0.
    auto STAGE = [&](int kt, int pb) {
        const int k0 = kt * BK;
        const bool second = (k0 >= E_N);   // x_{t-1} half
        #pragma unroll
        for (int cc = 0; cc < 2; ++cc) {
            int c   = wave + cc * 4;
            int row = c * 16 + l4;
            long rA = r0 + row - (second ? 1 : 0);
            if (second && zfix && row == 0) rA = -1;   // guard row (zeroed)
            const bf16* ga = xb + rA * E_N + (k0 & (E_N - 1)) + gq * 8;
            __builtin_amdgcn_global_load_lds(
                (const GLOBAL_AS void*)ga,
                (LDS_AS void*)&As[pb][c * 16][0], 16, 0, 0);
            const bf16* gb = Wt + (size_t)(n0 + row) * K2_N + k0 + gq * 8;
            __builtin_amdgcn_global_load_lds(
                (const GLOBAL_AS void*)gb,
                (LDS_AS void*)&Bs[pb][c * 16][0], 16, 0, 0);
        }
    };

    STAGE(0, 0);
    #pragma unroll
    for (int kt = 0; kt < K2_N / BK; ++kt) {
        const int cur = kt & 1;
        if (kt < K2_N / BK - 1) {
            STAGE(kt + 1, cur ^ 1);
            // current tile's 4 loads done; next tile's 4 stay in flight
            asm volatile("s_waitcnt vmcnt(4)" ::: "memory");
        } else {
            asm volatile("s_waitcnt vmcnt(0)" ::: "memory");
        }
        __builtin_amdgcn_sched_barrier(0);
        __builtin_amdgcn_s_barrier();          // all waves: cur tile ready
        __builtin_amdgcn_sched_barrier(0);

        bf16x8s a_frag[4], b_frag[4];
        #pragma unroll
        for (int mi = 0; mi < 4; ++mi)
            a_frag[mi] = *(const bf16x8s*)(&As[cur][wm + mi * 16 + l15][swq * 8]);
        #pragma unroll
        for (int ni = 0; ni < 4; ++ni)
            b_frag[ni] = *(const bf16x8s*)(&Bs[cur][wn + ni * 16 + l15][swq * 8]);
        // SWAPPED operands: D^T layout. Lane owns x-row (col dim = l15),
        // W-cols quad*4+j (row dim). Bit-identical element values.
        #pragma unroll
        for (int mi = 0; mi < 4; ++mi)
            #pragma unroll
            for (int ni = 0; ni < 4; ++ni)
                acc[mi][ni] = __builtin_amdgcn_mfma_f32_16x16x32_bf16(
                    b_frag[ni], a_frag[mi], acc[mi][ni], 0, 0, 0);

        __builtin_amdgcn_sched_barrier(0);
        __builtin_amdgcn_s_barrier();          // all waves done reading cur
        __builtin_amdgcn_sched_barrier(0);
        // (buffer cur is overwritten at iter kt+2's STAGE; any wave there has
        //  passed this barrier, so all waves' reads of cur are complete)
    }

    // --- epilogue: direct stores, no LDS ---
    // acc[mi][ni][j] = D[row = r0+wm+mi*16+l15][col = n0+wn+ni*16+quad*4+j]
    const int type  = n0 >> 8;          // 0=z(tanh,bf16) 1=f(sig,half) 2=o(sig,f32)
    const int cbase = n0 + wn - type * 256 + quad * 4;
    float4 bias4[4];
    #pragma unroll
    for (int ni = 0; ni < 4; ++ni)
        bias4[ni] = *(const float4*)&bvec[n0 + wn + ni * 16 + quad * 4];

    #pragma unroll
    for (int mi = 0; mi < 4; ++mi) {
        const size_t gr = (size_t)(r0 + wm + mi * 16 + l15) * H_N;
        #pragma unroll
        for (int ni = 0; ni < 4; ++ni) {
            const int col = cbase + ni * 16;
            float v0 = acc[mi][ni][0] + bias4[ni].x;
            float v1 = acc[mi][ni][1] + bias4[ni].y;
            float v2 = acc[mi][ni][2] + bias4[ni].z;
            float v3 = acc[mi][ni][3] + bias4[ni].w;
            if (type == 0) {
                bf16 a0 = __float2bfloat16(tanh_fast(v0));
                bf16 a1 = __float2bfloat16(tanh_fast(v1));
                bf16 a2 = __float2bfloat16(tanh_fast(v2));
                bf16 a3 = __float2bfloat16(tanh_fast(v3));
                uint2 pk;
                pk.x = (uint)*(ushort*)&a0 | ((uint)*(ushort*)&a1 << 16);
                pk.y = (uint)*(ushort*)&a2 | ((uint)*(ushort*)&a3 << 16);
                *(uint2*)(Zp + gr + col) = pk;
            } else if (type == 1) {
                __half a0 = __float2half(sigmoid_fast(v0));
                __half a1 = __float2half(sigmoid_fast(v1));
                __half a2 = __float2half(sigmoid_fast(v2));
                __half a3 = __float2half(sigmoid_fast(v3));
                uint2 pk;
                pk.x = (uint)*(ushort*)&a0 | ((uint)*(ushort*)&a1 << 16);
                pk.y = (uint)*(ushort*)&a2 | ((uint)*(ushort*)&a3 << 16);
                *(uint2*)(Fh + gr + col) = pk;
            } else {
                float4 vv = make_float4(sigmoid_fast(v0), sigmoid_fast(v1),
                                        sigmoid_fast(v2), sigmoid_fast(v3));
                *(float4*)(Oout + gr + col) = vv;
            }
        }
    }
}

// K2: per-chunk local scan. Block-per-chunk (2048 blocks), 1 col/thread,
// 8-deep explicit load batching (static reg indices -> no scratch).
__global__ __launch_bounds__(256) void scan_part1(
    const ushort* __restrict__ Zp, const ushort* __restrict__ Fh,
    float* __restrict__ Cend, float* __restrict__ Pprod)
{
    const int bc = blockIdx.x;          // chunk 0..2047
    const int h  = threadIdx.x;         // col
    size_t base = (size_t)bc * LCH * H_N + h;
    float c = 0.f, P = 1.f;
    #pragma unroll
    for (int tt = 0; tt < LCH; tt += 8) {
        ushort zr[8], fr[8];
        #pragma unroll
        for (int k = 0; k < 8; ++k) {
            zr[k] = Zp[base + (size_t)k * H_N];
            fr[k] = Fh[base + (size_t)k * H_N];
        }
        #pragma unroll
        for (int k = 0; k < 8; ++k) {
            float z = bf2f(zr[k]);
            float f = __half2float(*(const __half*)&fr[k]);
            c = f * c + (1.f - f) * z;
            P *= f;
        }
        base += (size_t)8 * H_N;
    }
    Cend[(size_t)bc * H_N + h]  = c;
    Pprod[(size_t)bc * H_N + h] = P;
}

// K3: sequential scan across chunks. 4 h-cols/thread, float4, unrolled.
__global__ __launch_bounds__(256) void scan_part2(
    const float* __restrict__ Cend, const float* __restrict__ Pprod,
    float* __restrict__ Cstart)
{
    const int gid = blockIdx.x * 256 + threadIdx.x;  // 0..2047
    const int b   = gid >> 6;
    const int hc  = (gid & 63) * 4;
    float4 cs = make_float4(0.f, 0.f, 0.f, 0.f);
    #pragma unroll 8
    for (int ch = 0; ch < CCH; ++ch) {
        size_t idx = (size_t)(b * CCH + ch) * H_N + hc;
        *(float4*)(Cstart + idx) = cs;
        float4 ce = *(const float4*)(Cend + idx);
        float4 pp = *(const float4*)(Pprod + idx);
        cs.x = ce.x + pp.x * cs.x;
        cs.y = ce.y + pp.y * cs.y;
        cs.z = ce.z + pp.z * cs.z;
        cs.w = ce.w + pp.w * cs.w;
    }
}

// K4: replay chunk. Block-per-chunk (2048 blocks), 1 col/thread, 8-deep
// load batching; o read fp32 from outH rows, h written over (same thread,
// program-ordered, addresses touched exactly once).
__global__ __launch_bounds__(256) void scan_part3(
    const ushort* __restrict__ Zp, const ushort* __restrict__ Fh,
    const float* __restrict__ Cstart, const int* __restrict__ mask,
    float* __restrict__ outH, float* __restrict__ outHid, float* __restrict__ outCell)
{
    const int bc = blockIdx.x;          // chunk 0..2047
    const int b  = bc >> 6;             // bc / CCH
    const int h  = threadIdx.x;
    float c = Cstart[(size_t)bc * H_N + h];
    int tgt = mask[b] - 1;
    tgt = (tgt < 0) ? 0 : ((tgt > S_N - 1) ? (S_N - 1) : tgt);
    const int s0 = (bc & (CCH - 1)) * LCH;
    size_t base = (size_t)bc * LCH * H_N + h;

    #pragma unroll
    for (int tt = 0; tt < LCH; tt += 8) {
        ushort zr[8], fr[8];
        float orr[8];
        #pragma unroll
        for (int k = 0; k < 8; ++k) {
            zr[k]  = Zp[base + (size_t)k * H_N];
            fr[k]  = Fh[base + (size_t)k * H_N];
            orr[k] = outH[base + (size_t)k * H_N];
        }
        #pragma unroll
        for (int k = 0; k < 8; ++k) {
            float z = bf2f(zr[k]);
            float f = __half2float(*(const __half*)&fr[k]);
            c = f * c + (1.f - f) * z;
            float hv = orr[k] * c;
            outH[base + (size_t)k * H_N] = hv;
            if (s0 + tt + k == tgt) {
                outHid[(size_t)b * H_N + h]  = hv;
                outCell[(size_t)b * H_N + h] = c;
            }
        }
        base += (size_t)8 * H_N;
    }
}

extern "C" void kernel_launch(void* const* d_in, const int* in_sizes, int n_in,
                              void* d_out, int out_size, void* d_ws, size_t ws_size,
                              hipStream_t stream) {
    const float* x = nullptr; const int* mask = nullptr;
    const float* W = nullptr; const float* bvec = nullptr;
    for (int i = 0; i < n_in; ++i) {
        switch (in_sizes[i]) {
            case M_N * E_N:     x    = (const float*)d_in[i]; break;
            case B_N:           mask = (const int*)d_in[i]; break;
            case K2_N * N3_N:   W    = (const float*)d_in[i]; break;
            case N3_N:          bvec = (const float*)d_in[i]; break;
        }
    }

    float* out     = (float*)d_out;
    float* outHid  = out + (size_t)M_N * H_N;
    float* outCell = outHid + (size_t)B_N * H_N;

    bf16*   xb = (bf16*)d_ws + 256;
    bf16*   Wt = xb + (size_t)M_N * E_N;
    bf16*   Zp = Wt + (size_t)N3_N * K2_N;
    __half* Fh = (__half*)(Zp + (size_t)M_N * H_N);
    float* Cend   = (float*)(Fh + (size_t)M_N * H_N);
    float* Pprod  = Cend + (size_t)B_N * CCH * H_N;
    float* Cstart = Pprod + (size_t)B_N * CCH * H_N;

    prep<<<8192 + 96, 256, 0, stream>>>(x, xb, W, Wt);

    gemm_act<<<(M_N / BM) * (N3_N / BN), 256, 0, stream>>>(xb, Wt, bvec, Zp, Fh, out);
    scan_part1<<<B_N * CCH, 256, 0, stream>>>((const ushort*)Zp, (const ushort*)Fh,
                                              Cend, Pprod);
    scan_part2<<<B_N * (H_N / 4) / 256, 256, 0, stream>>>(Cend, Pprod, Cstart);
    scan_part3<<<B_N * CCH, 256, 0, stream>>>((const ushort*)Zp, (const ushort*)Fh,
                                              Cstart, mask, out, outHid, outCell);
}